// Round 1
// baseline (225.530 us; speedup 1.0000x reference)
//
#include <hip/hip_runtime.h>
#include <math.h>

typedef __attribute__((ext_vector_type(8))) short bf16x8;
typedef __attribute__((ext_vector_type(4))) float f32x4;

#define Dd 256
#define Hh 1024
#define Kk 128
#define MROWS 16
#define LDI 280
#define LDH 1048
#define LDY 268

static __device__ __forceinline__ unsigned short f2bf(float f) {
    unsigned u = __builtin_bit_cast(unsigned, f);
    unsigned r = (u + 0x7fffu + ((u >> 16) & 1u)) >> 16;   // RNE
    return (unsigned short)r;
}

static __device__ __forceinline__ float fast_tanh(float x) {
    const float e = __expf(2.0f * x);
    return 1.0f - 2.0f / (e + 1.0f);
}

// ---- merged LDS-transpose pack (verified passing layouts) ------------------
__global__ __launch_bounds__(256) void pack_weights(
    const float* __restrict__ W1, const float* __restrict__ W2,
    unsigned short* __restrict__ W1P, unsigned short* __restrict__ W2P)
{
    __shared__ unsigned short tile[128 * 33];
    const int tid = threadIdx.x;
    const int b = blockIdx.x;
    if (b < 128) {
        const int kst = b & 7;
        const int wpp = b >> 3;
        const int n0 = wpp * 64;
        const int k0 = kst * 32;
#pragma unroll
        for (int it = 0; it < 8; ++it) {
            const int i = it * 256 + tid;
            const int kk = i >> 6, nn = i & 63;
            tile[kk * 65 + nn] = f2bf(W1[(size_t)(k0 + kk) * Hh + n0 + nn]);
        }
        __syncthreads();
#pragma unroll
        for (int it = 0; it < 8; ++it) {
            const int i = it * 256 + tid;
            const int ct = i >> 9;
            const int lane = (i >> 3) & 63;
            const int j = i & 7;
            const int kk = (lane >> 4) * 8 + j;
            const int nn = ct * 16 + (lane & 15);
            W1P[(size_t)b * 2048 + i] = tile[kk * 65 + nn];
        }
    } else {
        const int u = b - 128;
        const int kseg = u & 7;
        const int w = u >> 3;
        const int n0 = w * 32;
        const int k0 = kseg * 128;
#pragma unroll
        for (int it = 0; it < 16; ++it) {
            const int i = it * 256 + tid;
            const int kk = i >> 5, nn = i & 31;
            tile[kk * 33 + nn] = f2bf(W2[(size_t)(k0 + kk) * Dd + n0 + nn]);
        }
        __syncthreads();
#pragma unroll
        for (int it = 0; it < 16; ++it) {
            const int i = it * 256 + tid;
            const int kst = i >> 10;
            const int ct = (i >> 9) & 1;
            const int lane = (i >> 3) & 63;
            const int j = i & 7;
            const int kk = kst * 32 + (lane >> 4) * 8 + j;
            const int nn = ct * 16 + (lane & 15);
            W2P[(size_t)u * 4096 + i] = tile[kk * 33 + nn];
        }
    }
}

// R20: base = R19 (44.7 µs). Theory: per-CU ingress pinned at ~31 B/cyc ≈
// 128B-line/4cyc L1 fill rate. Attack the fill count two ways, both
// bitwise-identical numerics (accumulation order preserved; R12 lesson):
//  (a) pin 96 KB of the 1 MB weight stream in LDS (GEMM1 kst0 = 64 KB,
//      GEMM2 kseg0/kst0-1 = 32 KB), peel those iterations -> -9.4% fills/eval
//  (b) __builtin_nontemporal_load on remaining weight loads: if gfx950 `nt`
//      skips L1 allocation, ingress can rise toward the ~64 B/cyc TA path.
// Live set stays < ~50 regs (64-tier spill lesson: R4-R7/R15/R17/R20).
__global__ __launch_bounds__(1024, 4) void ode_fused(
    const float* __restrict__ x,
    const unsigned short* __restrict__ W1P,
    const float* __restrict__ b1,
    const unsigned short* __restrict__ W2P,
    const float* __restrict__ b2,
    const int* __restrict__ indices,
    float* __restrict__ out)
{
    __shared__ __align__(16) unsigned short in_bf[MROWS * LDI];
    __shared__ __align__(16) unsigned short hid[MROWS * LDH];
    __shared__ float b1s[Hh];
    __shared__ float b2s[Dd];
    __shared__ __align__(16) unsigned short w1pin[16 * 2048];   // 64 KB: kst0, 4 ct frags per wave
    __shared__ __align__(16) unsigned short w2pin[16 * 1024];   // 32 KB: kseg0 kst0-1 per wave

    const int tid  = threadIdx.x;
    const int lane = tid & 63;
    const int w    = tid >> 6;      // wave 0..15
    const int quad = lane >> 4;
    const int l16  = lane & 15;
    const int row0 = blockIdx.x * MROWS;

    for (int i = tid; i < Hh; i += 1024) b1s[i] = b1[i];
    for (int i = tid; i < Dd; i += 1024) b2s[i] = b2[i];

    const unsigned short* w1w = W1P + (size_t)w * 16384 + (size_t)lane * 8;
    const unsigned short* w2w = W2P + (size_t)(w >> 1) * 32768
                                    + (size_t)(w & 1) * 512 + (size_t)lane * 8;

    float yv[4], av[4], k1v[4];
    const int scol = w * 16 + quad * 4;
    {
        const float4 v = *(const float4*)&x[(size_t)(row0 + l16) * Dd + scol];
        yv[0] = v.x; yv[1] = v.y; yv[2] = v.z; yv[3] = v.w;
        const unsigned u0 = (unsigned)f2bf(v.x) | ((unsigned)f2bf(v.y) << 16);
        const unsigned u1 = (unsigned)f2bf(v.z) | ((unsigned)f2bf(v.w) << 16);
        *(uint2*)&in_bf[l16 * LDI + scol] = make_uint2(u0, u1);
    }
    // one-time pin of first-k weight fragments (wave-private regions)
#pragma unroll
    for (int ct = 0; ct < 4; ++ct)
        *(bf16x8*)&w1pin[w * 2048 + ct * 512 + lane * 8] =
            __builtin_nontemporal_load((const bf16x8*)(w1w + (size_t)ct * 512));
#pragma unroll
    for (int kst = 0; kst < 2; ++kst)
        *(bf16x8*)&w2pin[w * 1024 + kst * 512 + lane * 8] =
            __builtin_nontemporal_load((const bf16x8*)(w2w + (size_t)kst * 1024));
    __syncthreads();

    const float h  = 1.0f;
    const float h6 = h / 6.0f, h2 = h * 0.5f, h46 = 4.0f * h / 6.0f;

#pragma unroll 1
    for (int e = 0; e < 3; ++e) {
        // ---- GEMM1: hid cols [w*64,+64) = tanh(in_bf @ W1 + b1)
        f32x4 acc[4] = {};
        {   // kst = 0 from pinned LDS (same k-order as before -> bit-identical)
            const bf16x8 bf = *(const bf16x8*)&in_bf[l16 * LDI + quad * 8];
            bf16x8 aw[4];
#pragma unroll
            for (int ct = 0; ct < 4; ++ct)
                aw[ct] = *(const bf16x8*)&w1pin[w * 2048 + ct * 512 + lane * 8];
#pragma unroll
            for (int ct = 0; ct < 4; ++ct)
                acc[ct] = __builtin_amdgcn_mfma_f32_16x16x32_bf16(
                    aw[ct], bf, acc[ct], 0, 0, 0);
        }
#pragma unroll 2
        for (int kst = 1; kst < 8; ++kst) {
            const bf16x8 bf = *(const bf16x8*)&in_bf[l16 * LDI + kst * 32 + quad * 8];
            bf16x8 aw[4];
#pragma unroll
            for (int ct = 0; ct < 4; ++ct)
                aw[ct] = __builtin_nontemporal_load(
                    (const bf16x8*)(w1w + (size_t)(kst * 4 + ct) * 512));
#pragma unroll
            for (int ct = 0; ct < 4; ++ct)
                acc[ct] = __builtin_amdgcn_mfma_f32_16x16x32_bf16(
                    aw[ct], bf, acc[ct], 0, 0, 0);
        }
#pragma unroll
        for (int ct = 0; ct < 4; ++ct) {
            const int col = w * 64 + ct * 16 + quad * 4;
            const float4 bb = *(const float4*)&b1s[col];
            const unsigned short h0 = f2bf(fast_tanh(acc[ct][0] + bb.x));
            const unsigned short h1 = f2bf(fast_tanh(acc[ct][1] + bb.y));
            const unsigned short h2b = f2bf(fast_tanh(acc[ct][2] + bb.z));
            const unsigned short h3b = f2bf(fast_tanh(acc[ct][3] + bb.w));
            const unsigned u0 = (unsigned)h0 | ((unsigned)h1 << 16);
            const unsigned u1 = (unsigned)h2b | ((unsigned)h3b << 16);
            *(uint2*)&hid[l16 * LDH + col] = make_uint2(u0, u1);
        }
        __syncthreads();

        // ---- GEMM2: F for state cols [w*16,+16) = hid @ W2 + b2
        f32x4 acc2 = {};
        {   // kseg = 0: kst 0,1 from pinned LDS; kst 2,3 from global (NT)
#pragma unroll
            for (int kst = 0; kst < 2; ++kst) {
                const bf16x8 bh = *(const bf16x8*)&hid[l16 * LDH + kst * 32 + quad * 8];
                const bf16x8 aw = *(const bf16x8*)&w2pin[w * 1024 + kst * 512 + lane * 8];
                acc2 = __builtin_amdgcn_mfma_f32_16x16x32_bf16(aw, bh, acc2, 0, 0, 0);
            }
#pragma unroll
            for (int kst = 2; kst < 4; ++kst) {
                const bf16x8 bh = *(const bf16x8*)&hid[l16 * LDH + kst * 32 + quad * 8];
                const bf16x8 aw = __builtin_nontemporal_load(
                    (const bf16x8*)(w2w + (size_t)kst * 1024));
                acc2 = __builtin_amdgcn_mfma_f32_16x16x32_bf16(aw, bh, acc2, 0, 0, 0);
            }
        }
#pragma unroll 2
        for (int kseg = 1; kseg < 8; ++kseg) {
#pragma unroll
            for (int kst = 0; kst < 4; ++kst) {
                const bf16x8 bh = *(const bf16x8*)&hid[l16 * LDH + kseg * 128 + kst * 32 + quad * 8];
                const bf16x8 aw = __builtin_nontemporal_load(
                    (const bf16x8*)(w2w + (size_t)(kseg * 4 + kst) * 1024));
                acc2 = __builtin_amdgcn_mfma_f32_16x16x32_bf16(aw, bh, acc2, 0, 0, 0);
            }
        }
        // ---- RK3 stage update (registers)
        {
            const float4 bb = *(const float4*)&b2s[scol];
            float tmp[4];
#pragma unroll
            for (int r = 0; r < 4; ++r) {
                const float F = acc2[r] + ((const float*)&bb)[r];
                if (e == 0) {
                    k1v[r] = F;
                    av[r] = yv[r] + h6 * F;
                    tmp[r] = yv[r] + h2 * F;
                } else if (e == 1) {
                    av[r] += h46 * F;
                    tmp[r] = yv[r] + h * (2.0f * F - k1v[r]);
                } else {
                    yv[r] = av[r] + h6 * F;
                    tmp[r] = yv[r];
                }
            }
            const unsigned u0 = (unsigned)f2bf(tmp[0]) | ((unsigned)f2bf(tmp[1]) << 16);
            const unsigned u1 = (unsigned)f2bf(tmp[2]) | ((unsigned)f2bf(tmp[3]) << 16);
            *(uint2*)&in_bf[l16 * LDI + scol] = make_uint2(u0, u1);
        }
        __syncthreads();
    }

    // final state -> LDS (reuse hid as fp32) -> gather
    float* yf = (float*)hid;
    {
        float4 v;
        v.x = yv[0]; v.y = yv[1]; v.z = yv[2]; v.w = yv[3];
        *(float4*)&yf[l16 * LDY + scol] = v;
    }
    __syncthreads();

    for (int i = tid; i < MROWS * Kk; i += 1024) {
        const int row = i >> 7;
        const int kc  = i & (Kk - 1);
        const int gi  = (row0 + row) * Kk + kc;
        out[gi] = yf[row * LDY + indices[gi]];
    }
}

extern "C" void kernel_launch(void* const* d_in, const int* in_sizes, int n_in,
                              void* d_out, int out_size, void* d_ws, size_t ws_size,
                              hipStream_t stream)
{
    const float* x  = (const float*)d_in[0];
    const float* W1 = (const float*)d_in[1];
    const float* b1 = (const float*)d_in[2];
    const float* W2 = (const float*)d_in[3];
    const float* b2 = (const float*)d_in[4];
    const int* indices = (const int*)d_in[5];
    float* out = (float*)d_out;

    const int H = in_sizes[2];        // 1024
    const int D = in_sizes[4];        // 256
    const int B = in_sizes[0] / D;    // 4096

    unsigned short* W1P = (unsigned short*)d_ws;                 // 512 KB
    unsigned short* W2P = W1P + (size_t)H * D;                   // 512 KB

    pack_weights<<<192, 256, 0, stream>>>(W1, W2, W1P, W2P);

    ode_fused<<<B / MROWS, 1024, 0, stream>>>(x, W1P, b1, W2P, b2, indices, out);
}

// Round 2
// 169.550 us; speedup vs baseline: 1.3302x; 1.3302x over previous
//
#include <hip/hip_runtime.h>
#include <math.h>

typedef __attribute__((ext_vector_type(8))) short bf16x8;
typedef __attribute__((ext_vector_type(4))) float f32x4;

#define Dd 256
#define Hh 1024
#define Kk 128
#define MROWS 16
#define LDI 280
#define LDH 1048
#define LDY 268

static __device__ __forceinline__ unsigned short f2bf(float f) {
    unsigned u = __builtin_bit_cast(unsigned, f);
    unsigned r = (u + 0x7fffu + ((u >> 16) & 1u)) >> 16;   // RNE
    return (unsigned short)r;
}

static __device__ __forceinline__ float fast_tanh(float x) {
    const float e = __expf(2.0f * x);
    return 1.0f - 2.0f / (e + 1.0f);
}

// ---- merged LDS-transpose pack (verified passing layouts) ------------------
__global__ __launch_bounds__(256) void pack_weights(
    const float* __restrict__ W1, const float* __restrict__ W2,
    unsigned short* __restrict__ W1P, unsigned short* __restrict__ W2P)
{
    __shared__ unsigned short tile[128 * 33];
    const int tid = threadIdx.x;
    const int b = blockIdx.x;
    if (b < 128) {
        const int kst = b & 7;
        const int wpp = b >> 3;
        const int n0 = wpp * 64;
        const int k0 = kst * 32;
#pragma unroll
        for (int it = 0; it < 8; ++it) {
            const int i = it * 256 + tid;
            const int kk = i >> 6, nn = i & 63;
            tile[kk * 65 + nn] = f2bf(W1[(size_t)(k0 + kk) * Hh + n0 + nn]);
        }
        __syncthreads();
#pragma unroll
        for (int it = 0; it < 8; ++it) {
            const int i = it * 256 + tid;
            const int ct = i >> 9;
            const int lane = (i >> 3) & 63;
            const int j = i & 7;
            const int kk = (lane >> 4) * 8 + j;
            const int nn = ct * 16 + (lane & 15);
            W1P[(size_t)b * 2048 + i] = tile[kk * 65 + nn];
        }
    } else {
        const int u = b - 128;
        const int kseg = u & 7;
        const int w = u >> 3;
        const int n0 = w * 32;
        const int k0 = kseg * 128;
#pragma unroll
        for (int it = 0; it < 16; ++it) {
            const int i = it * 256 + tid;
            const int kk = i >> 5, nn = i & 31;
            tile[kk * 33 + nn] = f2bf(W2[(size_t)(k0 + kk) * Dd + n0 + nn]);
        }
        __syncthreads();
#pragma unroll
        for (int it = 0; it < 16; ++it) {
            const int i = it * 256 + tid;
            const int kst = i >> 10;
            const int ct = (i >> 9) & 1;
            const int lane = (i >> 3) & 63;
            const int j = i & 7;
            const int kk = kst * 32 + (lane >> 4) * 8 + j;
            const int nn = ct * 16 + (lane & 15);
            W2P[(size_t)u * 4096 + i] = tile[kk * 33 + nn];
        }
    }
}

// R21: base = R19 (44.7 µs). R20 lesson: NT loads evict the weight stream
// from L2 (FETCH 7->262 MB) — NEVER perturb L2 residency. This round: cut
// fill-path bytes with bit-identical numerics.
//  - reg-pin GEMM1 kst0-3 (16 frags = 64 VGPR/lane, cap is 128 at 16 waves)
//  - LDS-pin GEMM1 kst4 (4 KB/wave) + GEMM2 kseg0 kst0-2 (3 KB/wave);
//    LDS total 162304 B of 163840.
//  - evals 2,3 skip 23 KB of the 64 KB/wave stream: 192->146 KB (-24%).
// Accumulation order kst0..7 / kseg0..7 unchanged -> absmax must stay 0.0625.
// Tripwire: VGPR=128 + WRITE_SIZE >> 2 MB => spill => halve reg-pin.
__global__ __launch_bounds__(1024, 4) void ode_fused(
    const float* __restrict__ x,
    const unsigned short* __restrict__ W1P,
    const float* __restrict__ b1,
    const unsigned short* __restrict__ W2P,
    const float* __restrict__ b2,
    const int* __restrict__ indices,
    float* __restrict__ out)
{
    __shared__ __align__(16) unsigned short in_bf[MROWS * LDI];
    __shared__ __align__(16) unsigned short hid[MROWS * LDH];
    __shared__ float b1s[Hh];
    __shared__ float b2s[Dd];
    __shared__ __align__(16) unsigned short w1pin[16 * 2048];   // 64 KB: GEMM1 kst4, 4 frags/wave
    __shared__ __align__(16) unsigned short w2pin[16 * 1536];   // 48 KB: GEMM2 kseg0 kst0-2

    const int tid  = threadIdx.x;
    const int lane = tid & 63;
    const int w    = tid >> 6;      // wave 0..15
    const int quad = lane >> 4;
    const int l16  = lane & 15;
    const int row0 = blockIdx.x * MROWS;

    for (int i = tid; i < Hh; i += 1024) b1s[i] = b1[i];
    for (int i = tid; i < Dd; i += 1024) b2s[i] = b2[i];

    const unsigned short* w1w = W1P + (size_t)w * 16384 + (size_t)lane * 8;
    const unsigned short* w2w = W2P + (size_t)(w >> 1) * 32768
                                    + (size_t)(w & 1) * 512 + (size_t)lane * 8;

    float yv[4], av[4], k1v[4];
    const int scol = w * 16 + quad * 4;
    {
        const float4 v = *(const float4*)&x[(size_t)(row0 + l16) * Dd + scol];
        yv[0] = v.x; yv[1] = v.y; yv[2] = v.z; yv[3] = v.w;
        const unsigned u0 = (unsigned)f2bf(v.x) | ((unsigned)f2bf(v.y) << 16);
        const unsigned u1 = (unsigned)f2bf(v.z) | ((unsigned)f2bf(v.w) << 16);
        *(uint2*)&in_bf[l16 * LDI + scol] = make_uint2(u0, u1);
    }

    // ---- one-time pins (plain loads; L2-resident stream untouched) ----
    bf16x8 wp[16];                       // GEMM1 kst0-3, static-indexed only
#pragma unroll
    for (int i = 0; i < 16; ++i)
        wp[i] = *(const bf16x8*)(w1w + (size_t)i * 512);
#pragma unroll
    for (int ct = 0; ct < 4; ++ct)
        *(bf16x8*)&w1pin[w * 2048 + ct * 512 + lane * 8] =
            *(const bf16x8*)(w1w + (size_t)(16 + ct) * 512);
#pragma unroll
    for (int kst = 0; kst < 3; ++kst)
        *(bf16x8*)&w2pin[w * 1536 + kst * 512 + lane * 8] =
            *(const bf16x8*)(w2w + (size_t)kst * 1024);
    __syncthreads();

    const float h  = 1.0f;
    const float h6 = h / 6.0f, h2 = h * 0.5f, h46 = 4.0f * h / 6.0f;

#pragma unroll 1
    for (int e = 0; e < 3; ++e) {
        // ---- GEMM1: hid cols [w*64,+64) = tanh(in_bf @ W1 + b1)
        f32x4 acc[4] = {};
        // kst 0-3 from pinned registers (same k-order -> bit-identical)
#pragma unroll
        for (int kst = 0; kst < 4; ++kst) {
            const bf16x8 bf = *(const bf16x8*)&in_bf[l16 * LDI + kst * 32 + quad * 8];
#pragma unroll
            for (int ct = 0; ct < 4; ++ct)
                acc[ct] = __builtin_amdgcn_mfma_f32_16x16x32_bf16(
                    wp[kst * 4 + ct], bf, acc[ct], 0, 0, 0);
        }
        // kst 4 from pinned LDS
        {
            const bf16x8 bf = *(const bf16x8*)&in_bf[l16 * LDI + 4 * 32 + quad * 8];
#pragma unroll
            for (int ct = 0; ct < 4; ++ct) {
                const bf16x8 aw = *(const bf16x8*)&w1pin[w * 2048 + ct * 512 + lane * 8];
                acc[ct] = __builtin_amdgcn_mfma_f32_16x16x32_bf16(
                    aw, bf, acc[ct], 0, 0, 0);
            }
        }
        // kst 5-7 streamed from L2
#pragma unroll 2
        for (int kst = 5; kst < 8; ++kst) {
            const bf16x8 bf = *(const bf16x8*)&in_bf[l16 * LDI + kst * 32 + quad * 8];
            bf16x8 aw[4];
#pragma unroll
            for (int ct = 0; ct < 4; ++ct)
                aw[ct] = *(const bf16x8*)(w1w + (size_t)(kst * 4 + ct) * 512);
#pragma unroll
            for (int ct = 0; ct < 4; ++ct)
                acc[ct] = __builtin_amdgcn_mfma_f32_16x16x32_bf16(
                    aw[ct], bf, acc[ct], 0, 0, 0);
        }
#pragma unroll
        for (int ct = 0; ct < 4; ++ct) {
            const int col = w * 64 + ct * 16 + quad * 4;
            const float4 bb = *(const float4*)&b1s[col];
            const unsigned short h0 = f2bf(fast_tanh(acc[ct][0] + bb.x));
            const unsigned short h1 = f2bf(fast_tanh(acc[ct][1] + bb.y));
            const unsigned short h2b = f2bf(fast_tanh(acc[ct][2] + bb.z));
            const unsigned short h3b = f2bf(fast_tanh(acc[ct][3] + bb.w));
            const unsigned u0 = (unsigned)h0 | ((unsigned)h1 << 16);
            const unsigned u1 = (unsigned)h2b | ((unsigned)h3b << 16);
            *(uint2*)&hid[l16 * LDH + col] = make_uint2(u0, u1);
        }
        __syncthreads();

        // ---- GEMM2: F for state cols [w*16,+16) = hid @ W2 + b2
        f32x4 acc2 = {};
        // kseg 0: kst 0-2 from pinned LDS, kst 3 streamed
        {
#pragma unroll
            for (int kst = 0; kst < 3; ++kst) {
                const bf16x8 bh = *(const bf16x8*)&hid[l16 * LDH + kst * 32 + quad * 8];
                const bf16x8 aw = *(const bf16x8*)&w2pin[w * 1536 + kst * 512 + lane * 8];
                acc2 = __builtin_amdgcn_mfma_f32_16x16x32_bf16(aw, bh, acc2, 0, 0, 0);
            }
            {
                const bf16x8 bh = *(const bf16x8*)&hid[l16 * LDH + 3 * 32 + quad * 8];
                const bf16x8 aw = *(const bf16x8*)(w2w + (size_t)3 * 1024);
                acc2 = __builtin_amdgcn_mfma_f32_16x16x32_bf16(aw, bh, acc2, 0, 0, 0);
            }
        }
#pragma unroll 2
        for (int kseg = 1; kseg < 8; ++kseg) {
#pragma unroll
            for (int kst = 0; kst < 4; ++kst) {
                const bf16x8 bh = *(const bf16x8*)&hid[l16 * LDH + kseg * 128 + kst * 32 + quad * 8];
                const bf16x8 aw = *(const bf16x8*)(w2w + (size_t)(kseg * 4 + kst) * 1024);
                acc2 = __builtin_amdgcn_mfma_f32_16x16x32_bf16(aw, bh, acc2, 0, 0, 0);
            }
        }
        // ---- RK3 stage update (registers)
        {
            const float4 bb = *(const float4*)&b2s[scol];
            float tmp[4];
#pragma unroll
            for (int r = 0; r < 4; ++r) {
                const float F = acc2[r] + ((const float*)&bb)[r];
                if (e == 0) {
                    k1v[r] = F;
                    av[r] = yv[r] + h6 * F;
                    tmp[r] = yv[r] + h2 * F;
                } else if (e == 1) {
                    av[r] += h46 * F;
                    tmp[r] = yv[r] + h * (2.0f * F - k1v[r]);
                } else {
                    yv[r] = av[r] + h6 * F;
                    tmp[r] = yv[r];
                }
            }
            const unsigned u0 = (unsigned)f2bf(tmp[0]) | ((unsigned)f2bf(tmp[1]) << 16);
            const unsigned u1 = (unsigned)f2bf(tmp[2]) | ((unsigned)f2bf(tmp[3]) << 16);
            *(uint2*)&in_bf[l16 * LDI + scol] = make_uint2(u0, u1);
        }
        __syncthreads();
    }

    // final state -> LDS (reuse hid as fp32) -> gather
    float* yf = (float*)hid;
    {
        float4 v;
        v.x = yv[0]; v.y = yv[1]; v.z = yv[2]; v.w = yv[3];
        *(float4*)&yf[l16 * LDY + scol] = v;
    }
    __syncthreads();

    for (int i = tid; i < MROWS * Kk; i += 1024) {
        const int row = i >> 7;
        const int kc  = i & (Kk - 1);
        const int gi  = (row0 + row) * Kk + kc;
        out[gi] = yf[row * LDY + indices[gi]];
    }
}

extern "C" void kernel_launch(void* const* d_in, const int* in_sizes, int n_in,
                              void* d_out, int out_size, void* d_ws, size_t ws_size,
                              hipStream_t stream)
{
    const float* x  = (const float*)d_in[0];
    const float* W1 = (const float*)d_in[1];
    const float* b1 = (const float*)d_in[2];
    const float* W2 = (const float*)d_in[3];
    const float* b2 = (const float*)d_in[4];
    const int* indices = (const int*)d_in[5];
    float* out = (float*)d_out;

    const int H = in_sizes[2];        // 1024
    const int D = in_sizes[4];        // 256
    const int B = in_sizes[0] / D;    // 4096

    unsigned short* W1P = (unsigned short*)d_ws;                 // 512 KB
    unsigned short* W2P = W1P + (size_t)H * D;                   // 512 KB

    pack_weights<<<192, 256, 0, stream>>>(W1, W2, W1P, W2P);

    ode_fused<<<B / MROWS, 1024, 0, stream>>>(x, W1P, b1, W2P, b2, indices, out);
}

// Round 9
// 153.419 us; speedup vs baseline: 1.4700x; 1.1051x over previous
//
#include <hip/hip_runtime.h>
#include <math.h>

typedef __attribute__((ext_vector_type(8))) short bf16x8;
typedef __attribute__((ext_vector_type(4))) float f32x4;

#define Dd 256
#define Hh 1024
#define Kk 128
#define MROWS 16
#define LDI 280
#define LDH 1048
#define LDY 268

static __device__ __forceinline__ unsigned short f2bf(float f) {
    unsigned u = __builtin_bit_cast(unsigned, f);
    unsigned r = (u + 0x7fffu + ((u >> 16) & 1u)) >> 16;   // RNE
    return (unsigned short)r;
}

static __device__ __forceinline__ float fast_tanh(float x) {
    const float e = __expf(2.0f * x);
    return 1.0f - 2.0f / (e + 1.0f);
}

// ---- merged LDS-transpose pack (verified passing layouts) ------------------
__global__ __launch_bounds__(256) void pack_weights(
    const float* __restrict__ W1, const float* __restrict__ W2,
    unsigned short* __restrict__ W1P, unsigned short* __restrict__ W2P)
{
    __shared__ unsigned short tile[128 * 33];
    const int tid = threadIdx.x;
    const int b = blockIdx.x;
    if (b < 128) {
        const int kst = b & 7;
        const int wpp = b >> 3;
        const int n0 = wpp * 64;
        const int k0 = kst * 32;
#pragma unroll
        for (int it = 0; it < 8; ++it) {
            const int i = it * 256 + tid;
            const int kk = i >> 6, nn = i & 63;
            tile[kk * 65 + nn] = f2bf(W1[(size_t)(k0 + kk) * Hh + n0 + nn]);
        }
        __syncthreads();
#pragma unroll
        for (int it = 0; it < 8; ++it) {
            const int i = it * 256 + tid;
            const int ct = i >> 9;
            const int lane = (i >> 3) & 63;
            const int j = i & 7;
            const int kk = (lane >> 4) * 8 + j;
            const int nn = ct * 16 + (lane & 15);
            W1P[(size_t)b * 2048 + i] = tile[kk * 65 + nn];
        }
    } else {
        const int u = b - 128;
        const int kseg = u & 7;
        const int w = u >> 3;
        const int n0 = w * 32;
        const int k0 = kseg * 128;
#pragma unroll
        for (int it = 0; it < 16; ++it) {
            const int i = it * 256 + tid;
            const int kk = i >> 5, nn = i & 31;
            tile[kk * 33 + nn] = f2bf(W2[(size_t)(k0 + kk) * Dd + n0 + nn]);
        }
        __syncthreads();
#pragma unroll
        for (int it = 0; it < 16; ++it) {
            const int i = it * 256 + tid;
            const int kst = i >> 10;
            const int ct = (i >> 9) & 1;
            const int lane = (i >> 3) & 63;
            const int j = i & 7;
            const int kk = kst * 32 + (lane >> 4) * 8 + j;
            const int nn = ct * 16 + (lane & 15);
            W2P[(size_t)u * 4096 + i] = tile[kk * 33 + nn];
        }
    }
}

// R28 == R22 resubmitted (R3-R8 benches were GPUAcquisitionTimeouts; no
// data since R21). Mechanism refined: whether hipcc reads the 2nd
// launch-bounds arg as waves/EU or (CUDA-compat) blocks/CU, (1024,4)
// resolves to an 8-waves/EU register target -> 64-VGPR allocator cap ->
// the 64-VGPR wp[16] reg-pin spilled everything (R21: VGPR=64, WRITE
// 161 MB scratch). With LDS 162 KB only 1 block/CU is resident anyway
// (4 waves/EU) -> legal budget is 128 VGPR, enforced by the 1024-thread
// first arg alone. So: drop the second arg, keep the pins:
//  - reg-pin GEMM1 kst0-3 (16 frags = 64 VGPR/lane)
//  - LDS-pin GEMM1 kst4 (4 KB/wave) + GEMM2 kseg0 kst0-2 (3 KB/wave)
//  - streamed GEMM1 loads interleaved (1 aw in flight) to cut peak pressure;
//    TLP from 16 waves hides latency, fill pipe is the bottleneck anyway.
// Numerics: same k-order, same bytes -> absmax must stay exactly 0.0625.
// Tripwire: VGPR still 64 or WRITE_SIZE >> 2 MB -> revert to LDS-only pin.
__global__ __launch_bounds__(1024) void ode_fused(
    const float* __restrict__ x,
    const unsigned short* __restrict__ W1P,
    const float* __restrict__ b1,
    const unsigned short* __restrict__ W2P,
    const float* __restrict__ b2,
    const int* __restrict__ indices,
    float* __restrict__ out)
{
    __shared__ __align__(16) unsigned short in_bf[MROWS * LDI];
    __shared__ __align__(16) unsigned short hid[MROWS * LDH];
    __shared__ float b1s[Hh];
    __shared__ float b2s[Dd];
    __shared__ __align__(16) unsigned short w1pin[16 * 2048];   // 64 KB: GEMM1 kst4, 4 frags/wave
    __shared__ __align__(16) unsigned short w2pin[16 * 1536];   // 48 KB: GEMM2 kseg0 kst0-2

    const int tid  = threadIdx.x;
    const int lane = tid & 63;
    const int w    = tid >> 6;      // wave 0..15
    const int quad = lane >> 4;
    const int l16  = lane & 15;
    const int row0 = blockIdx.x * MROWS;

    for (int i = tid; i < Hh; i += 1024) b1s[i] = b1[i];
    for (int i = tid; i < Dd; i += 1024) b2s[i] = b2[i];

    const unsigned short* w1w = W1P + (size_t)w * 16384 + (size_t)lane * 8;
    const unsigned short* w2w = W2P + (size_t)(w >> 1) * 32768
                                    + (size_t)(w & 1) * 512 + (size_t)lane * 8;

    float yv[4], av[4], k1v[4];
    const int scol = w * 16 + quad * 4;
    {
        const float4 v = *(const float4*)&x[(size_t)(row0 + l16) * Dd + scol];
        yv[0] = v.x; yv[1] = v.y; yv[2] = v.z; yv[3] = v.w;
        const unsigned u0 = (unsigned)f2bf(v.x) | ((unsigned)f2bf(v.y) << 16);
        const unsigned u1 = (unsigned)f2bf(v.z) | ((unsigned)f2bf(v.w) << 16);
        *(uint2*)&in_bf[l16 * LDI + scol] = make_uint2(u0, u1);
    }

    // ---- one-time pins (plain loads; L2-resident stream untouched) ----
    bf16x8 wp[16];                       // GEMM1 kst0-3, static-indexed only
#pragma unroll
    for (int i = 0; i < 16; ++i)
        wp[i] = *(const bf16x8*)(w1w + (size_t)i * 512);
#pragma unroll
    for (int ct = 0; ct < 4; ++ct)
        *(bf16x8*)&w1pin[w * 2048 + ct * 512 + lane * 8] =
            *(const bf16x8*)(w1w + (size_t)(16 + ct) * 512);
#pragma unroll
    for (int kst = 0; kst < 3; ++kst)
        *(bf16x8*)&w2pin[w * 1536 + kst * 512 + lane * 8] =
            *(const bf16x8*)(w2w + (size_t)kst * 1024);
    __syncthreads();

    const float h  = 1.0f;
    const float h6 = h / 6.0f, h2 = h * 0.5f, h46 = 4.0f * h / 6.0f;

#pragma unroll 1
    for (int e = 0; e < 3; ++e) {
        // ---- GEMM1: hid cols [w*64,+64) = tanh(in_bf @ W1 + b1)
        f32x4 acc[4] = {};
        // kst 0-3 from pinned registers (same k-order -> bit-identical)
#pragma unroll
        for (int kst = 0; kst < 4; ++kst) {
            const bf16x8 bf = *(const bf16x8*)&in_bf[l16 * LDI + kst * 32 + quad * 8];
#pragma unroll
            for (int ct = 0; ct < 4; ++ct)
                acc[ct] = __builtin_amdgcn_mfma_f32_16x16x32_bf16(
                    wp[kst * 4 + ct], bf, acc[ct], 0, 0, 0);
        }
        // kst 4 from pinned LDS
        {
            const bf16x8 bf = *(const bf16x8*)&in_bf[l16 * LDI + 4 * 32 + quad * 8];
#pragma unroll
            for (int ct = 0; ct < 4; ++ct) {
                const bf16x8 aw = *(const bf16x8*)&w1pin[w * 2048 + ct * 512 + lane * 8];
                acc[ct] = __builtin_amdgcn_mfma_f32_16x16x32_bf16(
                    aw, bf, acc[ct], 0, 0, 0);
            }
        }
        // kst 5-7 streamed from L2, one aw in flight (pressure over ILP)
#pragma unroll 1
        for (int kst = 5; kst < 8; ++kst) {
            const bf16x8 bf = *(const bf16x8*)&in_bf[l16 * LDI + kst * 32 + quad * 8];
#pragma unroll
            for (int ct = 0; ct < 4; ++ct) {
                const bf16x8 aw = *(const bf16x8*)(w1w + (size_t)(kst * 4 + ct) * 512);
                acc[ct] = __builtin_amdgcn_mfma_f32_16x16x32_bf16(
                    aw, bf, acc[ct], 0, 0, 0);
            }
        }
#pragma unroll
        for (int ct = 0; ct < 4; ++ct) {
            const int col = w * 64 + ct * 16 + quad * 4;
            const float4 bb = *(const float4*)&b1s[col];
            const unsigned short h0 = f2bf(fast_tanh(acc[ct][0] + bb.x));
            const unsigned short h1 = f2bf(fast_tanh(acc[ct][1] + bb.y));
            const unsigned short h2b = f2bf(fast_tanh(acc[ct][2] + bb.z));
            const unsigned short h3b = f2bf(fast_tanh(acc[ct][3] + bb.w));
            const unsigned u0 = (unsigned)h0 | ((unsigned)h1 << 16);
            const unsigned u1 = (unsigned)h2b | ((unsigned)h3b << 16);
            *(uint2*)&hid[l16 * LDH + col] = make_uint2(u0, u1);
        }
        __syncthreads();

        // ---- GEMM2: F for state cols [w*16,+16) = hid @ W2 + b2
        f32x4 acc2 = {};
        // kseg 0: kst 0-2 from pinned LDS, kst 3 streamed
        {
#pragma unroll
            for (int kst = 0; kst < 3; ++kst) {
                const bf16x8 bh = *(const bf16x8*)&hid[l16 * LDH + kst * 32 + quad * 8];
                const bf16x8 aw = *(const bf16x8*)&w2pin[w * 1536 + kst * 512 + lane * 8];
                acc2 = __builtin_amdgcn_mfma_f32_16x16x32_bf16(aw, bh, acc2, 0, 0, 0);
            }
            {
                const bf16x8 bh = *(const bf16x8*)&hid[l16 * LDH + 3 * 32 + quad * 8];
                const bf16x8 aw = *(const bf16x8*)(w2w + (size_t)3 * 1024);
                acc2 = __builtin_amdgcn_mfma_f32_16x16x32_bf16(aw, bh, acc2, 0, 0, 0);
            }
        }
#pragma unroll 2
        for (int kseg = 1; kseg < 8; ++kseg) {
#pragma unroll
            for (int kst = 0; kst < 4; ++kst) {
                const bf16x8 bh = *(const bf16x8*)&hid[l16 * LDH + kseg * 128 + kst * 32 + quad * 8];
                const bf16x8 aw = *(const bf16x8*)(w2w + (size_t)(kseg * 4 + kst) * 1024);
                acc2 = __builtin_amdgcn_mfma_f32_16x16x32_bf16(aw, bh, acc2, 0, 0, 0);
            }
        }
        // ---- RK3 stage update (registers)
        {
            const float4 bb = *(const float4*)&b2s[scol];
            float tmp[4];
#pragma unroll
            for (int r = 0; r < 4; ++r) {
                const float F = acc2[r] + ((const float*)&bb)[r];
                if (e == 0) {
                    k1v[r] = F;
                    av[r] = yv[r] + h6 * F;
                    tmp[r] = yv[r] + h2 * F;
                } else if (e == 1) {
                    av[r] += h46 * F;
                    tmp[r] = yv[r] + h * (2.0f * F - k1v[r]);
                } else {
                    yv[r] = av[r] + h6 * F;
                    tmp[r] = yv[r];
                }
            }
            const unsigned u0 = (unsigned)f2bf(tmp[0]) | ((unsigned)f2bf(tmp[1]) << 16);
            const unsigned u1 = (unsigned)f2bf(tmp[2]) | ((unsigned)f2bf(tmp[3]) << 16);
            *(uint2*)&in_bf[l16 * LDI + scol] = make_uint2(u0, u1);
        }
        __syncthreads();
    }

    // final state -> LDS (reuse hid as fp32) -> gather
    float* yf = (float*)hid;
    {
        float4 v;
        v.x = yv[0]; v.y = yv[1]; v.z = yv[2]; v.w = yv[3];
        *(float4*)&yf[l16 * LDY + scol] = v;
    }
    __syncthreads();

    for (int i = tid; i < MROWS * Kk; i += 1024) {
        const int row = i >> 7;
        const int kc  = i & (Kk - 1);
        const int gi  = (row0 + row) * Kk + kc;
        out[gi] = yf[row * LDY + indices[gi]];
    }
}

extern "C" void kernel_launch(void* const* d_in, const int* in_sizes, int n_in,
                              void* d_out, int out_size, void* d_ws, size_t ws_size,
                              hipStream_t stream)
{
    const float* x  = (const float*)d_in[0];
    const float* W1 = (const float*)d_in[1];
    const float* b1 = (const float*)d_in[2];
    const float* W2 = (const float*)d_in[3];
    const float* b2 = (const float*)d_in[4];
    const int* indices = (const int*)d_in[5];
    float* out = (float*)d_out;

    const int H = in_sizes[2];        // 1024
    const int D = in_sizes[4];        // 256
    const int B = in_sizes[0] / D;    // 4096

    unsigned short* W1P = (unsigned short*)d_ws;                 // 512 KB
    unsigned short* W2P = W1P + (size_t)H * D;                   // 512 KB

    pack_weights<<<192, 256, 0, stream>>>(W1, W2, W1P, W2P);

    ode_fused<<<B / MROWS, 1024, 0, stream>>>(x, W1P, b1, W2P, b2, indices, out);
}

// Round 11
// 151.323 us; speedup vs baseline: 1.4904x; 1.0139x over previous
//
#include <hip/hip_runtime.h>
#include <math.h>

typedef __attribute__((ext_vector_type(8))) short bf16x8;
typedef __attribute__((ext_vector_type(4))) float f32x4;

#define Dd 256
#define Hh 1024
#define Kk 128
#define MROWS 16
#define LDI 280
#define LDH 1048
#define LDY 268

static __device__ __forceinline__ unsigned short f2bf(float f) {
    unsigned u = __builtin_bit_cast(unsigned, f);
    unsigned r = (u + 0x7fffu + ((u >> 16) & 1u)) >> 16;   // RNE
    return (unsigned short)r;
}

static __device__ __forceinline__ float fast_tanh(float x) {
    const float e = __expf(2.0f * x);
    return 1.0f - 2.0f / (e + 1.0f);
}

// ---- merged LDS-transpose pack (verified passing layouts) ------------------
__global__ __launch_bounds__(256) void pack_weights(
    const float* __restrict__ W1, const float* __restrict__ W2,
    unsigned short* __restrict__ W1P, unsigned short* __restrict__ W2P)
{
    __shared__ unsigned short tile[128 * 33];
    const int tid = threadIdx.x;
    const int b = blockIdx.x;
    if (b < 128) {
        const int kst = b & 7;
        const int wpp = b >> 3;
        const int n0 = wpp * 64;
        const int k0 = kst * 32;
#pragma unroll
        for (int it = 0; it < 8; ++it) {
            const int i = it * 256 + tid;
            const int kk = i >> 6, nn = i & 63;
            tile[kk * 65 + nn] = f2bf(W1[(size_t)(k0 + kk) * Hh + n0 + nn]);
        }
        __syncthreads();
#pragma unroll
        for (int it = 0; it < 8; ++it) {
            const int i = it * 256 + tid;
            const int ct = i >> 9;
            const int lane = (i >> 3) & 63;
            const int j = i & 7;
            const int kk = (lane >> 4) * 8 + j;
            const int nn = ct * 16 + (lane & 15);
            W1P[(size_t)b * 2048 + i] = tile[kk * 65 + nn];
        }
    } else {
        const int u = b - 128;
        const int kseg = u & 7;
        const int w = u >> 3;
        const int n0 = w * 32;
        const int k0 = kseg * 128;
#pragma unroll
        for (int it = 0; it < 16; ++it) {
            const int i = it * 256 + tid;
            const int kk = i >> 5, nn = i & 31;
            tile[kk * 33 + nn] = f2bf(W2[(size_t)(k0 + kk) * Dd + n0 + nn]);
        }
        __syncthreads();
#pragma unroll
        for (int it = 0; it < 16; ++it) {
            const int i = it * 256 + tid;
            const int kst = i >> 10;
            const int ct = (i >> 9) & 1;
            const int lane = (i >> 3) & 63;
            const int j = i & 7;
            const int kk = kst * 32 + (lane >> 4) * 8 + j;
            const int nn = ct * 16 + (lane & 15);
            W2P[(size_t)u * 4096 + i] = tile[kk * 33 + nn];
        }
    }
}

// R30 == R29 resubmitted (R10 bench was a GPUAcquisitionTimeout; no data).
// R29: tripwire executed. R22's run (R9) FALSIFIED the launch-bounds theory:
// __launch_bounds__(1024) with no 2nd arg STILL caps the allocator at 64
// VGPRs for 16-wave blocks (VGPR_Count=64, WRITE 108 MB scratch). LESSON:
// at 1024-thread blocks the register budget is 64 VGPRs, hard — reg-pinning
// weights (64 VGPR) can never fit next to the ~40-reg working set. Reverting
// to the proven R19 streaming structure + LDS-ONLY pin (validated correct in
// R21/R22: absmax exactly 0.0625):
//  - LDS-pin GEMM1 kst4 (64 KB) + GEMM2 kseg0 kst0-2 (48 KB) = 112 KB
//  - evals 2,3 skip 112 KB of the 1 MB/eval stream: 3072 -> 2848 KB (-7.3%)
//  - streamed loads restored to R19's batched aw[4] form (VGPR ~40, no spill)
// Next single-variable candidate if this lands: sc0/agent-scope streamed
// loads to bypass the L1 line-fill wall (measured 33 cyc per 1 KB wave-load
// == 8 lines x 4 cyc/line fill).
__global__ __launch_bounds__(1024) void ode_fused(
    const float* __restrict__ x,
    const unsigned short* __restrict__ W1P,
    const float* __restrict__ b1,
    const unsigned short* __restrict__ W2P,
    const float* __restrict__ b2,
    const int* __restrict__ indices,
    float* __restrict__ out)
{
    __shared__ __align__(16) unsigned short in_bf[MROWS * LDI];
    __shared__ __align__(16) unsigned short hid[MROWS * LDH];
    __shared__ float b1s[Hh];
    __shared__ float b2s[Dd];
    __shared__ __align__(16) unsigned short w1pin[16 * 2048];   // 64 KB: GEMM1 kst4, 4 frags/wave
    __shared__ __align__(16) unsigned short w2pin[16 * 1536];   // 48 KB: GEMM2 kseg0 kst0-2

    const int tid  = threadIdx.x;
    const int lane = tid & 63;
    const int w    = tid >> 6;      // wave 0..15
    const int quad = lane >> 4;
    const int l16  = lane & 15;
    const int row0 = blockIdx.x * MROWS;

    for (int i = tid; i < Hh; i += 1024) b1s[i] = b1[i];
    for (int i = tid; i < Dd; i += 1024) b2s[i] = b2[i];

    const unsigned short* w1w = W1P + (size_t)w * 16384 + (size_t)lane * 8;
    const unsigned short* w2w = W2P + (size_t)(w >> 1) * 32768
                                    + (size_t)(w & 1) * 512 + (size_t)lane * 8;

    float yv[4], av[4], k1v[4];
    const int scol = w * 16 + quad * 4;
    {
        const float4 v = *(const float4*)&x[(size_t)(row0 + l16) * Dd + scol];
        yv[0] = v.x; yv[1] = v.y; yv[2] = v.z; yv[3] = v.w;
        const unsigned u0 = (unsigned)f2bf(v.x) | ((unsigned)f2bf(v.y) << 16);
        const unsigned u1 = (unsigned)f2bf(v.z) | ((unsigned)f2bf(v.w) << 16);
        *(uint2*)&in_bf[l16 * LDI + scol] = make_uint2(u0, u1);
    }

    // ---- one-time LDS pins (plain loads; L2-resident stream untouched) ----
#pragma unroll
    for (int ct = 0; ct < 4; ++ct)
        *(bf16x8*)&w1pin[w * 2048 + ct * 512 + lane * 8] =
            *(const bf16x8*)(w1w + (size_t)(16 + ct) * 512);
#pragma unroll
    for (int kst = 0; kst < 3; ++kst)
        *(bf16x8*)&w2pin[w * 1536 + kst * 512 + lane * 8] =
            *(const bf16x8*)(w2w + (size_t)kst * 1024);
    __syncthreads();

    const float h  = 1.0f;
    const float h6 = h / 6.0f, h2 = h * 0.5f, h46 = 4.0f * h / 6.0f;

#pragma unroll 1
    for (int e = 0; e < 3; ++e) {
        // ---- GEMM1: hid cols [w*64,+64) = tanh(in_bf @ W1 + b1)
        f32x4 acc[4] = {};
        // kst 0-3 streamed from L2 (R19 batched form)
#pragma unroll 2
        for (int kst = 0; kst < 4; ++kst) {
            const bf16x8 bf = *(const bf16x8*)&in_bf[l16 * LDI + kst * 32 + quad * 8];
            bf16x8 aw[4];
#pragma unroll
            for (int ct = 0; ct < 4; ++ct)
                aw[ct] = *(const bf16x8*)(w1w + (size_t)(kst * 4 + ct) * 512);
#pragma unroll
            for (int ct = 0; ct < 4; ++ct)
                acc[ct] = __builtin_amdgcn_mfma_f32_16x16x32_bf16(
                    aw[ct], bf, acc[ct], 0, 0, 0);
        }
        // kst 4 from pinned LDS (same k-order -> bit-identical)
        {
            const bf16x8 bf = *(const bf16x8*)&in_bf[l16 * LDI + 4 * 32 + quad * 8];
#pragma unroll
            for (int ct = 0; ct < 4; ++ct) {
                const bf16x8 aw = *(const bf16x8*)&w1pin[w * 2048 + ct * 512 + lane * 8];
                acc[ct] = __builtin_amdgcn_mfma_f32_16x16x32_bf16(
                    aw, bf, acc[ct], 0, 0, 0);
            }
        }
        // kst 5-7 streamed from L2
#pragma unroll 2
        for (int kst = 5; kst < 8; ++kst) {
            const bf16x8 bf = *(const bf16x8*)&in_bf[l16 * LDI + kst * 32 + quad * 8];
            bf16x8 aw[4];
#pragma unroll
            for (int ct = 0; ct < 4; ++ct)
                aw[ct] = *(const bf16x8*)(w1w + (size_t)(kst * 4 + ct) * 512);
#pragma unroll
            for (int ct = 0; ct < 4; ++ct)
                acc[ct] = __builtin_amdgcn_mfma_f32_16x16x32_bf16(
                    aw[ct], bf, acc[ct], 0, 0, 0);
        }
#pragma unroll
        for (int ct = 0; ct < 4; ++ct) {
            const int col = w * 64 + ct * 16 + quad * 4;
            const float4 bb = *(const float4*)&b1s[col];
            const unsigned short h0 = f2bf(fast_tanh(acc[ct][0] + bb.x));
            const unsigned short h1 = f2bf(fast_tanh(acc[ct][1] + bb.y));
            const unsigned short h2b = f2bf(fast_tanh(acc[ct][2] + bb.z));
            const unsigned short h3b = f2bf(fast_tanh(acc[ct][3] + bb.w));
            const unsigned u0 = (unsigned)h0 | ((unsigned)h1 << 16);
            const unsigned u1 = (unsigned)h2b | ((unsigned)h3b << 16);
            *(uint2*)&hid[l16 * LDH + col] = make_uint2(u0, u1);
        }
        __syncthreads();

        // ---- GEMM2: F for state cols [w*16,+16) = hid @ W2 + b2
        f32x4 acc2 = {};
        // kseg 0: kst 0-2 from pinned LDS, kst 3 streamed
        {
#pragma unroll
            for (int kst = 0; kst < 3; ++kst) {
                const bf16x8 bh = *(const bf16x8*)&hid[l16 * LDH + kst * 32 + quad * 8];
                const bf16x8 aw = *(const bf16x8*)&w2pin[w * 1536 + kst * 512 + lane * 8];
                acc2 = __builtin_amdgcn_mfma_f32_16x16x32_bf16(aw, bh, acc2, 0, 0, 0);
            }
            {
                const bf16x8 bh = *(const bf16x8*)&hid[l16 * LDH + 3 * 32 + quad * 8];
                const bf16x8 aw = *(const bf16x8*)(w2w + (size_t)3 * 1024);
                acc2 = __builtin_amdgcn_mfma_f32_16x16x32_bf16(aw, bh, acc2, 0, 0, 0);
            }
        }
#pragma unroll 2
        for (int kseg = 1; kseg < 8; ++kseg) {
#pragma unroll
            for (int kst = 0; kst < 4; ++kst) {
                const bf16x8 bh = *(const bf16x8*)&hid[l16 * LDH + kseg * 128 + kst * 32 + quad * 8];
                const bf16x8 aw = *(const bf16x8*)(w2w + (size_t)(kseg * 4 + kst) * 1024);
                acc2 = __builtin_amdgcn_mfma_f32_16x16x32_bf16(aw, bh, acc2, 0, 0, 0);
            }
        }
        // ---- RK3 stage update (registers)
        {
            const float4 bb = *(const float4*)&b2s[scol];
            float tmp[4];
#pragma unroll
            for (int r = 0; r < 4; ++r) {
                const float F = acc2[r] + ((const float*)&bb)[r];
                if (e == 0) {
                    k1v[r] = F;
                    av[r] = yv[r] + h6 * F;
                    tmp[r] = yv[r] + h2 * F;
                } else if (e == 1) {
                    av[r] += h46 * F;
                    tmp[r] = yv[r] + h * (2.0f * F - k1v[r]);
                } else {
                    yv[r] = av[r] + h6 * F;
                    tmp[r] = yv[r];
                }
            }
            const unsigned u0 = (unsigned)f2bf(tmp[0]) | ((unsigned)f2bf(tmp[1]) << 16);
            const unsigned u1 = (unsigned)f2bf(tmp[2]) | ((unsigned)f2bf(tmp[3]) << 16);
            *(uint2*)&in_bf[l16 * LDI + scol] = make_uint2(u0, u1);
        }
        __syncthreads();
    }

    // final state -> LDS (reuse hid as fp32) -> gather
    float* yf = (float*)hid;
    {
        float4 v;
        v.x = yv[0]; v.y = yv[1]; v.z = yv[2]; v.w = yv[3];
        *(float4*)&yf[l16 * LDY + scol] = v;
    }
    __syncthreads();

    for (int i = tid; i < MROWS * Kk; i += 1024) {
        const int row = i >> 7;
        const int kc  = i & (Kk - 1);
        const int gi  = (row0 + row) * Kk + kc;
        out[gi] = yf[row * LDY + indices[gi]];
    }
}

extern "C" void kernel_launch(void* const* d_in, const int* in_sizes, int n_in,
                              void* d_out, int out_size, void* d_ws, size_t ws_size,
                              hipStream_t stream)
{
    const float* x  = (const float*)d_in[0];
    const float* W1 = (const float*)d_in[1];
    const float* b1 = (const float*)d_in[2];
    const float* W2 = (const float*)d_in[3];
    const float* b2 = (const float*)d_in[4];
    const int* indices = (const int*)d_in[5];
    float* out = (float*)d_out;

    const int H = in_sizes[2];        // 1024
    const int D = in_sizes[4];        // 256
    const int B = in_sizes[0] / D;    // 4096

    unsigned short* W1P = (unsigned short*)d_ws;                 // 512 KB
    unsigned short* W2P = W1P + (size_t)H * D;                   // 512 KB

    pack_weights<<<192, 256, 0, stream>>>(W1, W2, W1P, W2P);

    ode_fused<<<B / MROWS, 1024, 0, stream>>>(x, W1P, b1, W2P, b2, indices, out);
}

// Round 14
// 133.797 us; speedup vs baseline: 1.6856x; 1.1310x over previous
//
#include <hip/hip_runtime.h>
#include <math.h>

typedef __attribute__((ext_vector_type(8))) short bf16x8;
typedef __attribute__((ext_vector_type(4))) float f32x4;

#define Dd 256
#define Hh 1024
#define Kk 128
#define MROWS 16
#define LDI 280
#define LDH 1048
#define LDY 268

static __device__ __forceinline__ unsigned short f2bf(float f) {
    unsigned u = __builtin_bit_cast(unsigned, f);
    unsigned r = (u + 0x7fffu + ((u >> 16) & 1u)) >> 16;   // RNE
    return (unsigned short)r;
}

static __device__ __forceinline__ float fast_tanh(float x) {
    const float e = __expf(2.0f * x);
    return 1.0f - 2.0f / (e + 1.0f);
}

// ---- merged LDS-transpose pack (verified passing layouts) ------------------
__global__ __launch_bounds__(256) void pack_weights(
    const float* __restrict__ W1, const float* __restrict__ W2,
    unsigned short* __restrict__ W1P, unsigned short* __restrict__ W2P)
{
    __shared__ unsigned short tile[128 * 33];
    const int tid = threadIdx.x;
    const int b = blockIdx.x;
    if (b < 128) {
        const int kst = b & 7;
        const int wpp = b >> 3;
        const int n0 = wpp * 64;
        const int k0 = kst * 32;
#pragma unroll
        for (int it = 0; it < 8; ++it) {
            const int i = it * 256 + tid;
            const int kk = i >> 6, nn = i & 63;
            tile[kk * 65 + nn] = f2bf(W1[(size_t)(k0 + kk) * Hh + n0 + nn]);
        }
        __syncthreads();
#pragma unroll
        for (int it = 0; it < 8; ++it) {
            const int i = it * 256 + tid;
            const int ct = i >> 9;
            const int lane = (i >> 3) & 63;
            const int j = i & 7;
            const int kk = (lane >> 4) * 8 + j;
            const int nn = ct * 16 + (lane & 15);
            W1P[(size_t)b * 2048 + i] = tile[kk * 65 + nn];
        }
    } else {
        const int u = b - 128;
        const int kseg = u & 7;
        const int w = u >> 3;
        const int n0 = w * 32;
        const int k0 = kseg * 128;
#pragma unroll
        for (int it = 0; it < 16; ++it) {
            const int i = it * 256 + tid;
            const int kk = i >> 5, nn = i & 31;
            tile[kk * 33 + nn] = f2bf(W2[(size_t)(k0 + kk) * Dd + n0 + nn]);
        }
        __syncthreads();
#pragma unroll
        for (int it = 0; it < 16; ++it) {
            const int i = it * 256 + tid;
            const int kst = i >> 10;
            const int ct = (i >> 9) & 1;
            const int lane = (i >> 3) & 63;
            const int j = i & 7;
            const int kk = kst * 32 + (lane >> 4) * 8 + j;
            const int nn = ct * 16 + (lane & 15);
            W2P[(size_t)u * 4096 + i] = tile[kk * 33 + nn];
        }
    }
}

// R33 == R31 resubmitted (R12, R13 benches were GPUAcquisitionTimeouts).
// R31: POST-MORTEM R11: R29 (LDS-only pin, no wp[16]) showed the IDENTICAL
// spill signature as R22 (VGPR=64/SGPR=112/WRITE=108544 KB) => the scratch
// was never the reg-pin; the LOOP RESTRUCTURING (mid-splitting GEMM1 into
// 0-3/4/5-7 + partial kseg0 split) is what breaks R19's 40-reg codegen.
// (Also: SQ_LDS_BANK_CONFLICT is a constant artifact across all rounds.)
// This round: EXACT R0/R19 source (proven 44.7 us, VGPR 40, launch_bounds
// (1024,4) kept identical) with ONE minimal delta: tail-peel GEMM2 kseg7
// into a wave-private LDS pin (64 KB). GEMM1 untouched. kseg loop 0..6
// unchanged body, peeled kseg7 reads pinned aw. Same accumulation order,
// same bytes -> absmax must stay exactly 0.0625.
// Streamed bytes: 64 + 3*(1024-64) = 2944 vs 3072 KB (-4.2%).
// Predict: VGPR 40-48, WRITE ~2 MB, FETCH ~7.2 MB, dur 42.5-44 us.
// Tripwire: 64/112/108MB signature => any peel is toxic => final = exact R19.
__global__ __launch_bounds__(1024, 4) void ode_fused(
    const float* __restrict__ x,
    const unsigned short* __restrict__ W1P,
    const float* __restrict__ b1,
    const unsigned short* __restrict__ W2P,
    const float* __restrict__ b2,
    const int* __restrict__ indices,
    float* __restrict__ out)
{
    __shared__ __align__(16) unsigned short in_bf[MROWS * LDI];
    __shared__ __align__(16) unsigned short hid[MROWS * LDH];
    __shared__ float b1s[Hh];
    __shared__ float b2s[Dd];
    __shared__ __align__(16) unsigned short w2pin[16 * 2048];   // 64 KB: GEMM2 kseg7, wave-private

    const int tid  = threadIdx.x;
    const int lane = tid & 63;
    const int w    = tid >> 6;      // wave 0..15
    const int quad = lane >> 4;
    const int l16  = lane & 15;
    const int row0 = blockIdx.x * MROWS;

    for (int i = tid; i < Hh; i += 1024) b1s[i] = b1[i];
    for (int i = tid; i < Dd; i += 1024) b2s[i] = b2[i];

    float yv[4], av[4], k1v[4];
    const int scol = w * 16 + quad * 4;
    {
        const float4 v = *(const float4*)&x[(size_t)(row0 + l16) * Dd + scol];
        yv[0] = v.x; yv[1] = v.y; yv[2] = v.z; yv[3] = v.w;
        const unsigned u0 = (unsigned)f2bf(v.x) | ((unsigned)f2bf(v.y) << 16);
        const unsigned u1 = (unsigned)f2bf(v.z) | ((unsigned)f2bf(v.w) << 16);
        *(uint2*)&in_bf[l16 * LDI + scol] = make_uint2(u0, u1);
    }

    const unsigned short* w1w = W1P + (size_t)w * 16384 + (size_t)lane * 8;
    const unsigned short* w2w = W2P + (size_t)(w >> 1) * 32768
                                    + (size_t)(w & 1) * 512 + (size_t)lane * 8;

    // one-time wave-private pin of GEMM2 kseg7 (plain loads, L2 untouched)
#pragma unroll
    for (int kst = 0; kst < 4; ++kst)
        *(bf16x8*)&w2pin[w * 2048 + kst * 512 + lane * 8] =
            *(const bf16x8*)(w2w + (size_t)(28 + kst) * 1024);
    __syncthreads();

    const float h  = 1.0f;
    const float h6 = h / 6.0f, h2 = h * 0.5f, h46 = 4.0f * h / 6.0f;

#pragma unroll 1
    for (int e = 0; e < 3; ++e) {
        // ---- GEMM1: hid cols [w*64,+64) = tanh(in_bf @ W1 + b1)
        f32x4 acc[4] = {};
#pragma unroll 2
        for (int kst = 0; kst < 8; ++kst) {
            const bf16x8 bf = *(const bf16x8*)&in_bf[l16 * LDI + kst * 32 + quad * 8];
            bf16x8 aw[4];
#pragma unroll
            for (int ct = 0; ct < 4; ++ct)
                aw[ct] = *(const bf16x8*)(w1w + (size_t)(kst * 4 + ct) * 512);
#pragma unroll
            for (int ct = 0; ct < 4; ++ct)
                acc[ct] = __builtin_amdgcn_mfma_f32_16x16x32_bf16(
                    aw[ct], bf, acc[ct], 0, 0, 0);
        }
#pragma unroll
        for (int ct = 0; ct < 4; ++ct) {
            const int col = w * 64 + ct * 16 + quad * 4;
            const float4 bb = *(const float4*)&b1s[col];
            const unsigned short h0 = f2bf(fast_tanh(acc[ct][0] + bb.x));
            const unsigned short h1 = f2bf(fast_tanh(acc[ct][1] + bb.y));
            const unsigned short h2b = f2bf(fast_tanh(acc[ct][2] + bb.z));
            const unsigned short h3b = f2bf(fast_tanh(acc[ct][3] + bb.w));
            const unsigned u0 = (unsigned)h0 | ((unsigned)h1 << 16);
            const unsigned u1 = (unsigned)h2b | ((unsigned)h3b << 16);
            *(uint2*)&hid[l16 * LDH + col] = make_uint2(u0, u1);
        }
        __syncthreads();

        // ---- GEMM2: F for state cols [w*16,+16) = hid @ W2 + b2
        f32x4 acc2 = {};
#pragma unroll 2
        for (int kseg = 0; kseg < 7; ++kseg) {
#pragma unroll
            for (int kst = 0; kst < 4; ++kst) {
                const bf16x8 bh = *(const bf16x8*)&hid[l16 * LDH + kseg * 128 + kst * 32 + quad * 8];
                const bf16x8 aw = *(const bf16x8*)(w2w + (size_t)(kseg * 4 + kst) * 1024);
                acc2 = __builtin_amdgcn_mfma_f32_16x16x32_bf16(aw, bh, acc2, 0, 0, 0);
            }
        }
        // kseg 7 from pinned LDS (same k-order tail -> bit-identical)
#pragma unroll
        for (int kst = 0; kst < 4; ++kst) {
            const bf16x8 bh = *(const bf16x8*)&hid[l16 * LDH + 7 * 128 + kst * 32 + quad * 8];
            const bf16x8 aw = *(const bf16x8*)&w2pin[w * 2048 + kst * 512 + lane * 8];
            acc2 = __builtin_amdgcn_mfma_f32_16x16x32_bf16(aw, bh, acc2, 0, 0, 0);
        }
        // ---- RK3 stage update (registers)
        {
            const float4 bb = *(const float4*)&b2s[scol];
            float tmp[4];
#pragma unroll
            for (int r = 0; r < 4; ++r) {
                const float F = acc2[r] + ((const float*)&bb)[r];
                if (e == 0) {
                    k1v[r] = F;
                    av[r] = yv[r] + h6 * F;
                    tmp[r] = yv[r] + h2 * F;
                } else if (e == 1) {
                    av[r] += h46 * F;
                    tmp[r] = yv[r] + h * (2.0f * F - k1v[r]);
                } else {
                    yv[r] = av[r] + h6 * F;
                    tmp[r] = yv[r];
                }
            }
            const unsigned u0 = (unsigned)f2bf(tmp[0]) | ((unsigned)f2bf(tmp[1]) << 16);
            const unsigned u1 = (unsigned)f2bf(tmp[2]) | ((unsigned)f2bf(tmp[3]) << 16);
            *(uint2*)&in_bf[l16 * LDI + scol] = make_uint2(u0, u1);
        }
        __syncthreads();
    }

    // final state -> LDS (reuse hid as fp32) -> gather
    float* yf = (float*)hid;
    {
        float4 v;
        v.x = yv[0]; v.y = yv[1]; v.z = yv[2]; v.w = yv[3];
        *(float4*)&yf[l16 * LDY + scol] = v;
    }
    __syncthreads();

    for (int i = tid; i < MROWS * Kk; i += 1024) {
        const int row = i >> 7;
        const int kc  = i & (Kk - 1);
        const int gi  = (row0 + row) * Kk + kc;
        out[gi] = yf[row * LDY + indices[gi]];
    }
}

extern "C" void kernel_launch(void* const* d_in, const int* in_sizes, int n_in,
                              void* d_out, int out_size, void* d_ws, size_t ws_size,
                              hipStream_t stream)
{
    const float* x  = (const float*)d_in[0];
    const float* W1 = (const float*)d_in[1];
    const float* b1 = (const float*)d_in[2];
    const float* W2 = (const float*)d_in[3];
    const float* b2 = (const float*)d_in[4];
    const int* indices = (const int*)d_in[5];
    float* out = (float*)d_out;

    const int H = in_sizes[2];        // 1024
    const int D = in_sizes[4];        // 256
    const int B = in_sizes[0] / D;    // 4096

    unsigned short* W1P = (unsigned short*)d_ws;                 // 512 KB
    unsigned short* W2P = W1P + (size_t)H * D;                   // 512 KB

    pack_weights<<<192, 256, 0, stream>>>(W1, W2, W1P, W2P);

    ode_fused<<<B / MROWS, 1024, 0, stream>>>(x, W1P, b1, W2P, b2, indices, out);
}